// Round 11
// baseline (1087.074 us; speedup 1.0000x reference)
//
#include <hip/hip_runtime.h>

#define NN 256
#define BIGF 1e9f
#define NROWS_LDS 152                       // C rows cached in dynamic LDS (exact f32)
#define SMEM_BYTES (NROWS_LDS * 256 * 4)    // 155648 B <= 160 KiB
#define LDS_LIMIT (NROWS_LDS * 1024)

typedef float v2f __attribute__((ext_vector_type(2)));

// One DPP min stage; old = x so any invalid-lane behavior is fmin(x,x) = identity.
template <int CTRL>
__device__ __forceinline__ float dpp_fmin(float x) {
    int t = __builtin_amdgcn_update_dpp(__float_as_int(x), __float_as_int(x),
                                        CTRL, 0xf, 0xf, false);
    return fminf(x, __int_as_float(t));
}

// Wave-64 min broadcast to all lanes through lane 63. (Verified rounds 4-10.)
__device__ __forceinline__ float wave_min_bcast(float x) {
    x = dpp_fmin<0x111>(x);  // row_shr:1
    x = dpp_fmin<0x112>(x);  // row_shr:2
    x = dpp_fmin<0x114>(x);  // row_shr:4
    x = dpp_fmin<0x118>(x);  // row_shr:8
    x = dpp_fmin<0x142>(x);  // row_bcast:15
    x = dpp_fmin<0x143>(x);  // row_bcast:31
    return __int_as_float(__builtin_amdgcn_readlane(__float_as_int(x), 63));
}

// CDNA packed f32: per-half IEEE identical to v_add_f32; neg = exact sign flip,
// so pk_sub(a,b) == {a.x-b.x, a.y-b.y} bit-exactly.
__device__ __forceinline__ v2f pk_add(v2f a, v2f b) {
    v2f d;
    asm("v_pk_add_f32 %0, %1, %2" : "=v"(d) : "v"(a), "v"(b));
    return d;
}
__device__ __forceinline__ v2f pk_sub(v2f a, v2f b) {
    v2f d;
    asm("v_pk_add_f32 %0, %1, %2 neg_lo:[0,1] neg_hi:[0,1]" : "=v"(d) : "v"(a), "v"(b));
    return d;
}
// lane-masked selects: d = mask[lane] ? tv : fv   (mask = SGPR pair, 1 scalar op)
__device__ __forceinline__ float sel0f(float tv, unsigned long long m) {
    float d;
    asm("v_cndmask_b32 %0, 0, %1, %2" : "=v"(d) : "v"(tv), "s"(m));
    return d;
}
__device__ __forceinline__ float self_(float fv, float tv, unsigned long long m) {
    float d;
    asm("v_cndmask_b32 %0, %1, %2, %3" : "=v"(d) : "v"(fv), "v"(tv), "s"(m));
    return d;
}
__device__ __forceinline__ int seli_(int fv, int tv, unsigned long long m) {
    int d;
    asm("v_cndmask_b32 %0, %1, %2, %3" : "=v"(d) : "v"(fv), "v"(tv), "s"(m));
    return d;
}

extern "C" __global__ __launch_bounds__(64)
void lap_solve(const float* __restrict__ C, float* __restrict__ out) {
    extern __shared__ float rowc[];          // [NROWS_LDS][256]
    const int lane = threadIdx.x;
    const int base = lane * 4;               // 1-based columns base+1..base+4
    const int boff = base * 4 - 1024;        // (row<<10)+boff = byte off of ((row-1)*256+base)

    {   // stage rows 1..NROWS_LDS of C into LDS (exact f32 copy)
        const float4* src = (const float4*)C;
        float4*       dst = (float4*)rowc;
        #pragma unroll 8
        for (int idx = lane; idx < NROWS_LDS * 64; idx += 64) dst[idx] = src[idx];
    }
    __syncthreads();

    // Per-column state: packed pairs (slot0,slot1)/(slot2,slot3)
    v2f V01 = {0.f, 0.f}, V23 = {0.f, 0.f};   // col duals v[j]
    v2f A01 = {0.f, 0.f}, A23 = {0.f, 0.f};   // a_k = u[p_k]
    int p0 = 0, p1 = 0, p2 = 0, p3 = 0;       // matched row per col (0 = free)
    float vBIG = BIGF;                        // loop-invariant VGPR constant

    // prologue: row 1 (always LDS-resident)
    float4 r = *(const float4*)((const char*)rowc + ((1 << 10) + boff));

    for (int i = 1; i <= NN; ++i) {
        // m is the masked key (used slots drift from BIG, never observed).
        v2f M01 = {BIGF, BIGF}, M23 = {BIGF, BIGF};
        int w0 = 0, w1 = 0, w2 = 0, w3 = 0;   // way (pred col)
        // used-flags as wave-uniform 64-bit lane masks (SGPRs)
        unsigned long long Q0 = 0, Q1 = 0, Q2 = 0, Q3 = 0;
        float ui = 0.0f;            // u[i] accumulator (fresh row => 0)
        float u0 = 0.0f;            // u[i0] for current step (row i => 0)
        int   j0 = 0, jF = 0;

        for (int guard = 0; guard < 300; ++guard) {
            // scan: cur = (C1[i0][j] - u[i0]) - v[j]  (exact reference op order)
            v2f R01 = {r.x, r.y}, R23 = {r.z, r.w};
            v2f U = {u0, u0};
            v2f C01 = pk_sub(pk_sub(R01, U), V01);
            v2f C23 = pk_sub(pk_sub(R23, U), V23);

            // upd = (~used) & (cur < minv); minv=where(upd,cur,minv); way=where(upd,j0,way)
            unsigned long long cc0 = __ballot(C01.x < M01.x) & ~Q0;
            unsigned long long cc1 = __ballot(C01.y < M01.y) & ~Q1;
            unsigned long long cc2 = __ballot(C23.x < M23.x) & ~Q2;
            unsigned long long cc3 = __ballot(C23.y < M23.y) & ~Q3;
            int j0v;
            asm("v_mov_b32 %0, %1" : "=v"(j0v) : "s"(j0));
            M01.x = self_(M01.x, C01.x, cc0);  w0 = seli_(w0, j0v, cc0);
            M01.y = self_(M01.y, C01.y, cc1);  w1 = seli_(w1, j0v, cc1);
            M23.x = self_(M23.x, C23.x, cc2);  w2 = seli_(w2, j0v, cc2);
            M23.y = self_(M23.y, C23.y, cc3);  w3 = seli_(w3, j0v, cc3);

            // wave min over all 257 keys
            float bv = fminf(fminf(M01.x, M01.y), fminf(M23.x, M23.y));
            float gmin = wave_min_bcast(bv);

            // winner = lowest j with m == gmin; j = 4*lane + slot + 1, so
            // lexicographic (lane, slot) == first-index argmin semantics.
            unsigned long long b0 = __ballot(M01.x == gmin);
            unsigned long long b1 = __ballot(M01.y == gmin);
            unsigned long long b2 = __ballot(M23.x == gmin);
            unsigned long long b3 = __ballot(M23.y == gmin);
            unsigned long long anyb = b0 | b1 | b2 | b3;
            int wl = (int)__builtin_ctzll(anyb | 0x8000000000000000ULL);
            int sj = ((b0 >> wl) & 1) ? 0 : ((b1 >> wl) & 1) ? 1
                   : ((b2 >> wl) & 1) ? 2 : 3;
            int j1 = (wl << 2) + sj + 1;

            // winner's matched row -> issue next row load ASAP
            int   psel = (sj == 0) ? p0 : (sj == 1) ? p1 : (sj == 2) ? p2 : p3;
            int   pw   = __builtin_amdgcn_readlane(psel, wl);
            int   rowoff = pw << 10;
            float4 rn;
            if (rowoff <= LDS_LIMIT)         // rowoff==0 -> LDS OOB -> 0 (break follows)
                rn = *(const float4*)((const char*)rowc + (rowoff + boff));
            else
                rn = *(const float4*)((const char*)C + (rowoff + boff));

            // winner's u[p] (unused slot: unchanged this iteration -> frozen value)
            float asel = (sj == 0) ? A01.x : (sj == 1) ? A01.y : (sj == 2) ? A23.x : A23.y;
            float u0n  = __int_as_float(__builtin_amdgcn_readlane(__float_as_int(asel), wl));

            // exact reference dual updates (hide under the load):
            // used: u[p]+=d, v-=d (D=0 adds for unused match the reference's
            // scatter-add of where(used,d,0)); minv -= d (unconditional: exact
            // for unused, unobserved drift for used).
            float delta = gmin;
            float dv;
            asm("v_mov_b32 %0, %1" : "=v"(dv) : "s"(delta));
            v2f D01 = {sel0f(dv, Q0), sel0f(dv, Q1)};
            v2f D23 = {sel0f(dv, Q2), sel0f(dv, Q3)};
            A01 = pk_add(A01, D01);  V01 = pk_sub(V01, D01);
            A23 = pk_add(A23, D23);  V23 = pk_sub(V23, D23);
            v2f dd = {dv, dv};
            M01 = pk_sub(M01, dd);   M23 = pk_sub(M23, dd);
            ui += delta;                        // col 0 (row i) used each step

            // mark winner used (SALU) + force its key to BIG (one cndmask)
            unsigned long long bit = 1ull << wl;
            if (sj == 0)      { Q0 |= bit; M01.x = self_(M01.x, vBIG, bit); }
            else if (sj == 1) { Q1 |= bit; M01.y = self_(M01.y, vBIG, bit); }
            else if (sj == 2) { Q2 |= bit; M23.x = self_(M23.x, vBIG, bit); }
            else              { Q3 |= bit; M23.y = self_(M23.y, vBIG, bit); }

            j0 = j1; u0 = u0n; r = rn;
            if (rowoff == 0) { jF = j1; break; }    // winner column is free
        }

        // prefetch next outer iteration's row before the augment walk
        {
            int ni = (i < NN) ? (i + 1) : NN;
            int off = (ni << 10) + boff;
            if (ni <= NROWS_LDS) r = *(const float4*)((const char*)rowc + off);
            else                 r = *(const float4*)((const char*)C + off);
        }

        // augment: j is wave-uniform -> readlane per hop
        int j = jF;
        for (int g2w = 0; g2w < 300 && j != 0; ++g2w) {
            int oj = (j - 1) >> 2, sj2 = (j - 1) & 3;
            int wsel = (sj2 == 0) ? w0 : (sj2 == 1) ? w1 : (sj2 == 2) ? w2 : w3;
            int jn = __builtin_amdgcn_readlane(wsel, oj);
            int pn; float an;
            if (jn == 0) { pn = i; an = ui; }
            else {
                int on = (jn - 1) >> 2, sn = (jn - 1) & 3;
                int   ps = (sn == 0) ? p0 : (sn == 1) ? p1 : (sn == 2) ? p2 : p3;
                float as = (sn == 0) ? A01.x : (sn == 1) ? A01.y
                         : (sn == 2) ? A23.x : A23.y;
                pn = __builtin_amdgcn_readlane(ps, on);
                an = __int_as_float(__builtin_amdgcn_readlane(__float_as_int(as), on));
            }
            if (lane == oj) {
                if (sj2 == 0)      { p0 = pn; A01.x = an; }
                else if (sj2 == 1) { p1 = pn; A01.y = an; }
                else if (sj2 == 2) { p2 = pn; A23.x = an; }
                else               { p3 = pn; A23.y = an; }
            }
            j = jn;
        }
    }

    // emit 0/1 labelling: out[p[j]-1, j-1] = 1  (out pre-zeroed by memset)
    if (p0) out[(p0 - 1) * NN + base + 0] = 1.0f;
    if (p1) out[(p1 - 1) * NN + base + 1] = 1.0f;
    if (p2) out[(p2 - 1) * NN + base + 2] = 1.0f;
    if (p3) out[(p3 - 1) * NN + base + 3] = 1.0f;
}

extern "C" void kernel_launch(void* const* d_in, const int* in_sizes, int n_in,
                              void* d_out, int out_size, void* d_ws, size_t ws_size,
                              hipStream_t stream) {
    const float* C   = (const float*)d_in[0];
    float*       out = (float*)d_out;

    static_assert(SMEM_BYTES <= 160 * 1024, "LDS budget");
    (void)hipFuncSetAttribute((const void*)lap_solve,
                              hipFuncAttributeMaxDynamicSharedMemorySize,
                              SMEM_BYTES);

    (void)hipMemsetAsync(out, 0, NN * NN * sizeof(float), stream);
    lap_solve<<<dim3(1), dim3(64), SMEM_BYTES, stream>>>(C, out);
}

// Round 12
// 1014.388 us; speedup vs baseline: 1.0717x; 1.0717x over previous
//
#include <hip/hip_runtime.h>

#define NN 256
#define BIGF 1e9f
#define NROWS_LDS 152                       // C rows cached in dynamic LDS (exact f32)
#define SMEM_BYTES (NROWS_LDS * 256 * 4)    // 155648 B <= 160 KiB
#define LDS_LIMIT (NROWS_LDS * 1024)

// One DPP min stage; old = x so any invalid-lane behavior is fmin(x,x) = identity.
template <int CTRL>
__device__ __forceinline__ float dpp_fmin(float x) {
    int t = __builtin_amdgcn_update_dpp(__float_as_int(x), __float_as_int(x),
                                        CTRL, 0xf, 0xf, false);
    return fminf(x, __int_as_float(t));
}

// Wave-64 min broadcast to all lanes through lane 63. (Verified rounds 4-10.)
__device__ __forceinline__ float wave_min_bcast(float x) {
    x = dpp_fmin<0x111>(x);  // row_shr:1
    x = dpp_fmin<0x112>(x);  // row_shr:2
    x = dpp_fmin<0x114>(x);  // row_shr:4
    x = dpp_fmin<0x118>(x);  // row_shr:8
    x = dpp_fmin<0x142>(x);  // row_bcast:15
    x = dpp_fmin<0x143>(x);  // row_bcast:31
    return __int_as_float(__builtin_amdgcn_readlane(__float_as_int(x), 63));
}

extern "C" __global__ __launch_bounds__(64)
void lap_solve(const float* __restrict__ C, float* __restrict__ out) {
    extern __shared__ float rowc[];          // [NROWS_LDS][256]
    const int lane = threadIdx.x;
    const int base = lane * 4;               // 1-based columns base+1..base+4
    const int boff = base * 4 - 1024;        // (row<<10)+boff = byte off of ((row-1)*256+base)

    {   // stage rows 1..NROWS_LDS of C into LDS (exact f32 copy)
        const float4* src = (const float4*)C;
        float4*       dst = (float4*)rowc;
        #pragma unroll 8
        for (int idx = lane; idx < NROWS_LDS * 64; idx += 64) dst[idx] = src[idx];
    }
    __syncthreads();

    // All per-column state in registers (statically indexed):
    float v0 = 0.f, v1 = 0.f, v2 = 0.f, v3 = 0.f;   // col duals v[j]
    float a0 = 0.f, a1 = 0.f, a2 = 0.f, a3 = 0.f;   // a_k = u[p_k]
    int   p0 = 0,  p1 = 0,  p2 = 0,  p3 = 0;        // matched row per col (0 = free)

    // prologue: row 1 (always LDS-resident)
    float4 r = *(const float4*)((const char*)rowc + ((1 << 10) + boff));

    for (int i = 1; i <= NN; ++i) {
        // m is the masked key: used slots are set to BIGF at marking and then
        // drift as BIG - sum(delta) (unconditional subtraction below) — still
        // >> any real reduced cost, and every read of a used slot's m is
        // masked (scan q-guard, bv-min, ballot), so trajectory is bit-exact.
        float m0 = BIGF, m1 = BIGF, m2 = BIGF, m3 = BIGF;
        int   w0 = 0, w1 = 0, w2 = 0, w3 = 0;              // way (pred col)
        int   q0 = 0, q1 = 0, q2 = 0, q3 = 0;              // used flags
        float ui = 0.0f;            // u[i] accumulator (fresh row => 0)
        float u0 = 0.0f;            // u[i0] for current step (row i => 0)
        int   j0 = 0, jF = 0;

        for (int guard = 0; guard < 300; ++guard) {
            // cur = (C1[i0][j] - u[i0]) - v[j]  (exact reference op order)
            float c0 = (r.x - u0) - v0;
            float c1 = (r.y - u0) - v1;
            float c2 = (r.z - u0) - v2;
            float c3 = (r.w - u0) - v3;
            if (!q0 && c0 < m0) { m0 = c0; w0 = j0; }
            if (!q1 && c1 < m1) { m1 = c1; w1 = j0; }
            if (!q2 && c2 < m2) { m2 = c2; w2 = j0; }
            if (!q3 && c3 < m3) { m3 = c3; w3 = j0; }

            // local min (index pick runs parallel with the DPP chain)
            float bv = fminf(fminf(m0, m1), fminf(m2, m3));
            int   bk = (m0 == bv) ? 0 : (m1 == bv) ? 1 : (m2 == bv) ? 2 : 3;
            int   rc = (bk == 0) ? p0 : (bk == 1) ? p1 : (bk == 2) ? p2 : p3;
            float ra = (bk == 0) ? a0 : (bk == 1) ? a1 : (bk == 2) ? a2 : a3;
            // packed payload: row byte-offset (bits 10+) | column id (bits 0..9)
            // rc <= 256 -> rc<<10 disjoint from bj in [1,257]
            int   packed = (rc << 10) | (base + bk + 1);

            // wave min + lowest-lane winner = argmin first-index semantics
            float gmin = wave_min_bcast(bv);
            unsigned long long bal = __ballot(bv == gmin);
            int wl = (int)__builtin_ctzll(bal | 0x8000000000000000ULL);

            // ONE readlane gives row offset AND winner column
            int rdl    = __builtin_amdgcn_readlane(packed, wl);
            int rowoff = rdl & ~1023;
            int j1     = rdl & 1023;

            // issue next row load ASAP (rowoff==0 -> LDS OOB -> 0, break follows)
            float4 rn;
            if (rowoff <= LDS_LIMIT)
                rn = *(const float4*)((const char*)rowc + (rowoff + boff));
            else
                rn = *(const float4*)((const char*)C + (rowoff + boff));

            // winner's u[p] for next step's scan (hides under the load)
            float u0n = __int_as_float(__builtin_amdgcn_readlane(__float_as_int(ra), wl));

            float delta = gmin;                     // exact reference updates
            if (q0) { a0 += delta; v0 -= delta; }   // used: u[p]+=d, v-=d
            if (q1) { a1 += delta; v1 -= delta; }
            if (q2) { a2 += delta; v2 -= delta; }
            if (q3) { a3 += delta; v3 -= delta; }
            m0 -= delta;                            // unconditional: exact for
            m1 -= delta;                            // unused; masked drift for
            m2 -= delta;                            // used (never observed)
            m3 -= delta;
            ui += delta;                            // col 0 (row i) used each step

            // winner becomes used from next step; force its key to BIG.
            // (lane wl's own bk identifies the winning slot — same lane/slot
            // as the old (j1-1)>>2 / &3 derivation since j1 = 4*wl + bk + 1.)
            if (lane == wl) {
                if (bk == 0)      { q0 = 1; m0 = BIGF; }
                else if (bk == 1) { q1 = 1; m1 = BIGF; }
                else if (bk == 2) { q2 = 1; m2 = BIGF; }
                else              { q3 = 1; m3 = BIGF; }
            }

            j0 = j1; u0 = u0n; r = rn;
            if (rowoff == 0) { jF = j1; break; }    // winner column is free
        }

        // prefetch next outer iteration's row before the augment walk
        {
            int ni = (i < NN) ? (i + 1) : NN;
            int off = (ni << 10) + boff;
            if (ni <= NROWS_LDS) r = *(const float4*)((const char*)rowc + off);
            else                 r = *(const float4*)((const char*)C + off);
        }

        // augment: j is wave-uniform -> readlane per hop
        int j = jF;
        for (int g2w = 0; g2w < 300 && j != 0; ++g2w) {
            int oj = (j - 1) >> 2, sj = (j - 1) & 3;
            int wsel = (sj == 0) ? w0 : (sj == 1) ? w1 : (sj == 2) ? w2 : w3;
            int jn = __builtin_amdgcn_readlane(wsel, oj);
            int pn; float an;
            if (jn == 0) { pn = i; an = ui; }
            else {
                int on = (jn - 1) >> 2, sn = (jn - 1) & 3;
                int   ps = (sn == 0) ? p0 : (sn == 1) ? p1 : (sn == 2) ? p2 : p3;
                float as = (sn == 0) ? a0 : (sn == 1) ? a1 : (sn == 2) ? a2 : a3;
                pn = __builtin_amdgcn_readlane(ps, on);
                an = __int_as_float(__builtin_amdgcn_readlane(__float_as_int(as), on));
            }
            if (lane == oj) {
                if (sj == 0)      { p0 = pn; a0 = an; }
                else if (sj == 1) { p1 = pn; a1 = an; }
                else if (sj == 2) { p2 = pn; a2 = an; }
                else              { p3 = pn; a3 = an; }
            }
            j = jn;
        }
    }

    // emit 0/1 labelling: out[p[j]-1, j-1] = 1  (out pre-zeroed by memset)
    if (p0) out[(p0 - 1) * NN + base + 0] = 1.0f;
    if (p1) out[(p1 - 1) * NN + base + 1] = 1.0f;
    if (p2) out[(p2 - 1) * NN + base + 2] = 1.0f;
    if (p3) out[(p3 - 1) * NN + base + 3] = 1.0f;
}

extern "C" void kernel_launch(void* const* d_in, const int* in_sizes, int n_in,
                              void* d_out, int out_size, void* d_ws, size_t ws_size,
                              hipStream_t stream) {
    const float* C   = (const float*)d_in[0];
    float*       out = (float*)d_out;

    static_assert(SMEM_BYTES <= 160 * 1024, "LDS budget");
    (void)hipFuncSetAttribute((const void*)lap_solve,
                              hipFuncAttributeMaxDynamicSharedMemorySize,
                              SMEM_BYTES);

    (void)hipMemsetAsync(out, 0, NN * NN * sizeof(float), stream);
    lap_solve<<<dim3(1), dim3(64), SMEM_BYTES, stream>>>(C, out);
}